// Round 10
// baseline (212.165 us; speedup 1.0000x reference)
//
#include <hip/hip_runtime.h>

typedef unsigned short USH;
typedef short s16x8 __attribute__((ext_vector_type(8)));
typedef float f32x4 __attribute__((ext_vector_type(4)));
typedef float f32x16 __attribute__((ext_vector_type(16)));
typedef float f32x4v __attribute__((ext_vector_type(4)));
typedef unsigned int u32x4 __attribute__((ext_vector_type(4)));
// may_alias variants for ALL type-punned LDS/global accesses.
typedef s16x8 s16x8_a __attribute__((may_alias));
typedef f32x4v f32x4v_a __attribute__((may_alias));
typedef u32x4 u32x4_a __attribute__((may_alias));
typedef unsigned int u32_a __attribute__((may_alias));

#if __has_builtin(__builtin_amdgcn_exp2f)
#define EXP2F(x) __builtin_amdgcn_exp2f(x)  // raw v_exp_f32, no legalization
#else
#define EXP2F(x) __builtin_exp2f(x)
#endif

__device__ __forceinline__ USH f2bf(float f) {
  union { float f; unsigned int i; } c; c.f = f;
  unsigned int x = c.i;
  return (USH)((x + 0x7FFFu + ((x >> 16) & 1u)) >> 16);
}
__device__ __forceinline__ unsigned int pk_bf16(float a, float b) {
#if __has_builtin(__builtin_amdgcn_cvt_pk_bf16_f32)
  typedef USH ush2 __attribute__((ext_vector_type(2)));
  union { ush2 v; unsigned int u; } r;
  r.v = __builtin_amdgcn_cvt_pk_bf16_f32(a, b);
  return r.u;
#else
  union { float f; unsigned int i; } ca, cb; ca.f = a; cb.f = b;
  return ((ca.i + 0x8000u) >> 16) | ((cb.i + 0x8000u) & 0xFFFF0000u);
#endif
}

__device__ __forceinline__ f32x4 mfma16(s16x8 a, s16x8 b, f32x4 c) {
  return __builtin_amdgcn_mfma_f32_16x16x32_bf16(a, b, c, 0, 0, 0);
}
__device__ __forceinline__ f32x16 mfma32(s16x8 a, s16x8 b, f32x16 c) {
  return __builtin_amdgcn_mfma_f32_32x32x16_bf16(a, b, c, 0, 0, 0);
}

// async global->LDS, 16B per lane; LDS dest semantics: wave base + lane*16.
#if __has_builtin(__builtin_amdgcn_global_load_lds)
__device__ __forceinline__ void gld_lds16(const void* g, void* l) {
  __builtin_amdgcn_global_load_lds(
      static_cast<const unsigned int __attribute__((address_space(1)))*>(
          (const void __attribute__((address_space(1)))*)g),
      static_cast<unsigned int __attribute__((address_space(3)))*>(
          (void __attribute__((address_space(3)))*)l),
      16, 0, 0);
}
#else
__device__ __forceinline__ void gld_lds16(const void* g, void* l) {
  *(s16x8_a*)l = *(const s16x8_a*)g;  // fallback: synchronous copy, same addresses
}
#endif

// ------------- prep: WT[n][k] = bf16(W[k][n]) for the 4 weight matrices -------------
__global__ __launch_bounds__(256) void prep(
    const float* __restrict__ Wq, const float* __restrict__ Wk,
    const float* __restrict__ Wv, const float* __restrict__ Wo,
    USH* __restrict__ wsT) {
  __shared__ float tile[32][33];
  const int z = blockIdx.z;
  const int t = threadIdx.x;
  const float* W = (z == 0) ? Wq : (z == 1) ? Wk : (z == 2) ? Wv : Wo;
  USH* WT = wsT + (size_t)z * 262144;
  const int n0 = blockIdx.x * 32, k0 = blockIdx.y * 32;
  const int tx = t & 31, ty = t >> 5;  // 32 x 8
  #pragma unroll
  for (int i = 0; i < 4; ++i)
    tile[ty + i * 8][tx] = W[(size_t)(k0 + ty + i * 8) * 512 + n0 + tx];
  __syncthreads();
  #pragma unroll
  for (int i = 0; i < 4; ++i)
    WT[(size_t)(n0 + ty + i * 8) * 512 + k0 + tx] = f2bf(tile[tx][ty + i * 8]);
}

// ---------------- GEMM v4: out = A[M,512] * WT^T + bias ----------------
// (round-9: neutral-within-noise vs split prep; kept — one fewer dispatch.)
// m97-proven single-buffer 2-barrier structure with global_load_lds staging,
// __syncthreads-only (deterministic). XOR-swizzle both-sides (rule #21).
// MODE 0: A = att bf16; out float[m*512+n] (d_out fp32).
// MODE 1: A = x fp32 staged DIRECTLY, converted to bf16 frags in-register.
template <int MODE>
__global__ __launch_bounds__(256, 3) void gemm_bias(
    const USH* __restrict__ A, const float* __restrict__ A32,
    const USH* __restrict__ BT0,
    const float* __restrict__ b0, const float* __restrict__ b1,
    const float* __restrict__ b2,
    USH* __restrict__ oQ, USH* __restrict__ oKV, float* __restrict__ oF) {
  __shared__ __align__(16) USH As[MODE == 1 ? 16384 : 8192];
  __shared__ __align__(16) USH Bs[8192];  // [128 rows][64 USH] chunk-swizzled
  const int z = blockIdx.z;
  const USH* BT = BT0 + (size_t)z * 262144;
  const float* bias = (z == 0) ? b0 : ((z == 1) ? b1 : b2);
  USH* outb = (z == 0) ? oQ : (oKV + (size_t)(z - 1) * 4194304);
  const float qs = (MODE == 1 && z == 0) ? 0.06375871528132839f : 1.0f;

  const int t = threadIdx.x;
  const int w = t >> 6, lane = t & 63;
  const int c = lane & 15, g = lane >> 4;
  const int wm = w & 1, wn = w >> 1;
  const int m0 = blockIdx.x * 128, n0 = blockIdx.y * 128;

  f32x4 acc[4][4] = {};

  const int rB = w * 32 + (lane >> 3);                       // +j*8
  const int ccB = (((lane & 7) ^ ((lane >> 3) & 7))) * 8;
  const USH* BpD = BT + (size_t)(n0 + rB) * 512 + ccB;       // +kt*64 +j*4096
  USH* lB = Bs + w * 2048 + lane * 8;                        // +j*512

  const USH* ApD = nullptr;
  USH* lA0 = nullptr;
  const float* Ap32 = nullptr;
  USH* lA1 = nullptr;
  if (MODE == 0) {
    ApD = A + (size_t)(m0 + rB) * 512 + ccB;
    lA0 = As + w * 2048 + lane * 8;
  } else {
    const int rA = w * 4 + (lane >> 4);                      // +j*16
    const int gcA = (lane & 15) ^ (rA & 15);
    Ap32 = A32 + (size_t)(m0 + rA) * 512 + gcA * 4;          // +kt*64 +j*16*512
    lA1 = As + w * 512 + lane * 8;                           // +j*2048 (USH)
  }

  for (int kt = 0; kt < 8; ++kt) {
    __syncthreads();
    if (MODE == 0) {
      #pragma unroll
      for (int j = 0; j < 4; ++j) {
        gld_lds16(ApD + kt * 64 + j * 4096, lA0 + j * 512);
        gld_lds16(BpD + kt * 64 + j * 4096, lB + j * 512);
      }
    } else {
      #pragma unroll
      for (int j = 0; j < 8; ++j)
        gld_lds16(Ap32 + kt * 64 + (size_t)j * 8192, lA1 + j * 2048);
      #pragma unroll
      for (int j = 0; j < 4; ++j)
        gld_lds16(BpD + kt * 64 + j * 4096, lB + j * 512);
    }
    __syncthreads();
    #pragma unroll
    for (int ks = 0; ks < 2; ++ks) {
      s16x8 af[4], bfr[4];
      #pragma unroll
      for (int i = 0; i < 4; ++i) {
        const int ra = wm * 64 + i * 16 + c;
        const int rb = wn * 64 + i * 16 + c;
        if (MODE == 0) {
          af[i] = *(const s16x8_a*)(As + ra * 64 + ((ks * 4 + g) ^ (ra & 7)) * 8);
        } else {
          const int e = ks * 4 + g;
          const int p0 = (2 * e) ^ (ra & 15), p1 = (2 * e + 1) ^ (ra & 15);
          const float* Af = (const float*)As + ra * 64;
          const f32x4v lo = *(const f32x4v_a*)(Af + p0 * 4);
          const f32x4v hi = *(const f32x4v_a*)(Af + p1 * 4);
          union { u32x4 u; s16x8 v; } cvt;
          cvt.u.x = pk_bf16(lo.x, lo.y); cvt.u.y = pk_bf16(lo.z, lo.w);
          cvt.u.z = pk_bf16(hi.x, hi.y); cvt.u.w = pk_bf16(hi.z, hi.w);
          af[i] = cvt.v;
        }
        bfr[i] = *(const s16x8_a*)(Bs + rb * 64 + ((ks * 4 + g) ^ (rb & 7)) * 8);
      }
      #pragma unroll
      for (int mf = 0; mf < 4; ++mf)
        #pragma unroll
        for (int nf = 0; nf < 4; ++nf)
          acc[mf][nf] = mfma16(af[mf], bfr[nf], acc[mf][nf]);
    }
  }

  #pragma unroll
  for (int nf = 0; nf < 4; ++nf) {
    const int n = n0 + wn * 64 + nf * 16 + c;
    const float bv = bias[n];
    #pragma unroll
    for (int mf = 0; mf < 4; ++mf)
      #pragma unroll
      for (int r = 0; r < 4; ++r) {
        const int m = m0 + wm * 64 + mf * 16 + g * 4 + r;
        const float v = (acc[mf][nf][r] + bv) * qs;
        if (MODE == 0) {
          oF[(size_t)m * 512 + n] = v;
        } else {
          const int bb = m >> 12, s = m & 4095, h = n >> 6, hd = n & 63;
          if (z == 2)
            outb[(((size_t)(bb * 8 + h)) * 64 + hd) * 4096 + s] = f2bf(v);
          else
            outb[(((size_t)(bb * 8 + h)) * 4096 + s) * 64 + hd] = f2bf(v);
        }
      }
  }
}

// ---------------- flash attention v15: 32x32 swapped-QK, in-register P ----------------
// v14 (97.4us, 705 TF) was latency-bound on the per-iter chain; non-attn is
// harness-floor (~106us invariant). v15 ports the guide's verified 8-warp
// 32x32 structure (m214/T12): with mfma_f32_32x32x16_bf16, D-col = lane&31 =
// qrow is LANE-LOCAL -> P needs no LDS round-trip. P packed via cvt_pk; the
// only redistribution is lane<->lane+32 (__shfl_xor 32). l via ones-MFMA now
// lands per-lane (no lbuf broadcast). MFMA/iter/wave 72->40 (same FLOPs).
// Word mapping (derived from verified D layout row=(r&3)+8(r>>2)+4*hq):
//   lane packs P_i = pk(st[2i],st[2i+1]), X_i = shfl_xor(P_i,32); B-frag for
//   key-slice ks: hq=0 -> {P[4ks],P[4ks+1],X[4ks],X[4ks+1]},
//                 hq=1 -> {X[4ks+2],X[4ks+3],P[4ks+2],P[4ks+3]}.
// 256 thr / 4 waves x 32 qrows = 128 qrows/block; grid (32,16) = 512 blocks
// = 2/CU. KVBLK=128, K LDS [128key][64d] + V [64hd][128key], XOR-swizzled,
// dbuf = 64 KB. One __syncthreads/iter; QK(kb+1) issued before SMPV(kb)
// (stA/stB ping-pong). Epilogue: coalesced store via LDS transpose in dead Ks.
// Q pre-scaled by sc*log2e -> p = exp2(s).
__global__ __launch_bounds__(256, 2) void attn(const USH* __restrict__ Qbuf,
                                               const USH* __restrict__ kv,
                                               USH* __restrict__ att) {
  __shared__ __align__(16) USH Ks[2 * 8192];   // [buf][128 key][64 d] swz
  __shared__ __align__(16) USH Vt[2 * 8192];   // [buf][64 hd][128 key] swz

  const int t = threadIdx.x;
  const int w = t >> 6, lane = t & 63;
  const int cq = lane & 31, hq = lane >> 5;
  // XCD-aware remap, bijective on [0,512): each XCD owns 2 bh -> KV in L2.
  const int linear = blockIdx.x + (blockIdx.y << 5);
  const int xcd = linear & 7, idx = linear >> 3;   // idx in [0,64)
  const int bh = xcd + ((idx >> 5) << 3);
  const int bb = bh >> 3, hh = bh & 7;
  const size_t base = (size_t)bh * 262144;  // 4096*64
  const USH* Q = Qbuf + base;
  const USH* K = kv + base;                 // [S,Hd]
  const USH* V = kv + 4194304 + base;       // [Hd,S] (pre-transposed)
  const int q0 = (idx & 31) * 128 + w * 32;

  // Q fragments: B-operand of S^T = K*Q^T. B[k = t4*16 + hq*8 + j][n = cq]
  // = Q[q0+cq][t4*16 + hq*8 + j] — lane-local load, 4x s16x8.
  s16x8 qB[4];
  #pragma unroll
  for (int t4 = 0; t4 < 4; ++t4)
    qB[t4] = *(const s16x8_a*)(Q + (size_t)(q0 + cq) * 64 + t4 * 16 + hq * 8);

  // all-ones A-fragment for l = sum_key P (every D row = l[qrow])
  s16x8 ones;
  #pragma unroll
  for (int j = 0; j < 8; ++j) ones[j] = (short)0x3F80;

  f32x16 o[2] = {};   // O^T[hd(hb,r,hq)][qrow=cq], hb = hd/32
  f32x16 ol = {};     // l in every reg; use [0]

  // --- DMA lane mappings (4 waves, 4 calls each per K and V per tile) ---
  // K call j: byte j*4096 + t*16 -> row = j*32 + (t>>3), phys chunk t&7;
  // source global chunk = (t&7) ^ (row&7)  (row&7 j-invariant).
  const int rK = t >> 3;
  const USH* gK0 = K + (size_t)rK * 64 + (((t & 7) ^ (rK & 7)) * 8);  // +kt*8192 +j*2048
  // V call j: hd = j*16 + (t>>4), phys chunk t&15; src chunk ^(hd&7).
  const int rV = t >> 4;
  const USH* gV0 = V + (size_t)rV * 4096 + (((t & 15) ^ (rV & 7)) * 8); // +kt*128 +j*65536
  USH* lK = Ks + t * 8;   // +buf +j*2048
  USH* lV = Vt + t * 8;   // +buf +j*2048

  auto DMA = [&](int kt, int buf) {
    #pragma unroll
    for (int j = 0; j < 4; ++j) {
      gld_lds16(gK0 + (size_t)kt * 8192 + j * 2048, lK + buf + j * 2048);
      gld_lds16(gV0 + (size_t)kt * 128 + (size_t)j * 65536, lV + buf + j * 2048);
    }
  };

  // S^T[key 32][qrow 32] for key-block kb: A = K rows (lane cq = key), 4 d-steps.
  auto QK = [&](int kb, int buf) -> f32x16 {
    f32x16 st = {};
    #pragma unroll
    for (int t4 = 0; t4 < 4; ++t4) {
      const s16x8 ka = *(const s16x8_a*)(
          Ks + buf + (kb * 32 + cq) * 64 + (((2 * t4 + hq) ^ (cq & 7)) * 8));
      st = mfma32(ka, qB[t4], st);
    }
    return st;
  };

  // exp2 + pack + lane-swap + PV + l for key-block kb.
  auto SMPV = [&](f32x16 st, int kb, int buf) {
    unsigned int P[8], X[8];
    #pragma unroll
    for (int i = 0; i < 8; ++i)
      P[i] = pk_bf16(EXP2F(st[2 * i]), EXP2F(st[2 * i + 1]));
    #pragma unroll
    for (int i = 0; i < 8; ++i)
      X[i] = __shfl_xor(P[i], 32);
    #pragma unroll
    for (int ks = 0; ks < 2; ++ks) {
      union { u32x4 u; s16x8 v; } bf;
      bf.u.x = hq ? X[4 * ks + 2] : P[4 * ks];
      bf.u.y = hq ? X[4 * ks + 3] : P[4 * ks + 1];
      bf.u.z = hq ? P[4 * ks + 2] : X[4 * ks];
      bf.u.w = hq ? P[4 * ks + 3] : X[4 * ks + 1];
      const s16x8 bks = bf.v;
      #pragma unroll
      for (int hb = 0; hb < 2; ++hb) {
        const s16x8 va = *(const s16x8_a*)(
            Vt + buf + (hb * 32 + cq) * 128 +
            (((4 * kb + 2 * ks + hq) ^ (cq & 7)) * 8));
        o[hb] = mfma32(va, bks, o[hb]);
      }
      ol = mfma32(ones, bks, ol);
    }
  };

  // prologue: tile 0 -> buf 0
  DMA(0, 0);

  for (int kt = 0; kt < 32; ++kt) {
    const int buf = (kt & 1) * 8192;
    __syncthreads();  // implicit vmcnt(0): tile kt resident; buf^1 free
    if (kt < 31) DMA(kt + 1, buf ^ 8192);
    // in-iter pipeline: QK one key-block ahead of softmax+PV
    f32x16 stA = QK(0, buf);
    f32x16 stB = QK(1, buf);
    SMPV(stA, 0, buf);
    stA = QK(2, buf);
    SMPV(stB, 1, buf);
    stB = QK(3, buf);
    SMPV(stA, 2, buf);
    SMPV(stB, 3, buf);
  }

  // ---- epilogue: divide by l, transpose via dead Ks, coalesced store ----
  __syncthreads();  // all waves done with Ks/Vt
  USH* scr = Ks + w * 2304;  // per-wave [32 qrow][72 USH pad] (4608 B, 16B-aligned)
  const float linv = 1.0f / ol[0];
  #pragma unroll
  for (int hb = 0; hb < 2; ++hb)
    #pragma unroll
    for (int i = 0; i < 8; ++i) {
      const int hd = hb * 32 + 4 * hq + 2 * (i & 1) + 8 * (i >> 1);
      const unsigned int pw =
          pk_bf16(o[hb][2 * i] * linv, o[hb][2 * i + 1] * linv);
      *(u32_a*)(scr + cq * 72 + hd) = pw;
    }
  // wave-local in-order DS: no barrier needed before read-back
  #pragma unroll
  for (int p = 0; p < 4; ++p) {
    const int row = p * 8 + (lane >> 3), col = (lane & 7) * 8;
    const s16x8 v = *(const s16x8_a*)(scr + row * 72 + col);
    *(s16x8_a*)(att + ((size_t)(bb * 4096 + q0 + row)) * 512 + hh * 64 + col) = v;
  }
}

extern "C" void kernel_launch(void* const* d_in, const int* in_sizes, int n_in,
                              void* d_out, int out_size, void* d_ws, size_t ws_size,
                              hipStream_t stream) {
  (void)in_sizes; (void)n_in; (void)out_size; (void)ws_size;
  const float* x  = (const float*)d_in[0];
  const float* Wq = (const float*)d_in[1];
  const float* bq = (const float*)d_in[2];
  const float* Wk = (const float*)d_in[3];
  const float* bk = (const float*)d_in[4];
  const float* Wv = (const float*)d_in[5];
  const float* bv = (const float*)d_in[6];
  const float* Wo = (const float*)d_in[7];
  const float* bo = (const float*)d_in[8];
  USH* ws  = (USH*)d_ws;
  USH* wT  = ws;                       // 4 * 262144 bf16 transposed weights (2 MB)
  USH* kv  = ws + 1048576;             // K [B,H,S,Hd] + V [B,H,Hd,S] bf16 (16 MB)
  USH* att = ws + 1048576 + 8388608;   // 4194304 : attn out [B,S,D] bf16 (8 MB)
  float* outF = (float*)d_out;         // fp32 output (16 MB)
  USH* qscratch = (USH*)d_out;         // Q bf16 (8 MB), dead before final GEMM

  prep<<<dim3(16, 16, 4), 256, 0, stream>>>(Wq, Wk, Wv, Wo, wT);
  gemm_bias<1><<<dim3(64, 4, 3), 256, 0, stream>>>(nullptr, x, wT, bq, bk, bv,
                                                   qscratch, kv, nullptr);
  attn<<<dim3(32, 16), 256, 0, stream>>>(qscratch, kv, att);
  gemm_bias<0><<<dim3(64, 4, 1), 256, 0, stream>>>(att, nullptr, wT + 3 * 262144,
                                                   bo, bo, bo,
                                                   nullptr, nullptr, outF);
}

// Round 11
// 208.502 us; speedup vs baseline: 1.0176x; 1.0176x over previous
//
#include <hip/hip_runtime.h>

typedef unsigned short USH;
typedef short s16x8 __attribute__((ext_vector_type(8)));
typedef float f32x4 __attribute__((ext_vector_type(4)));
typedef float f32x16 __attribute__((ext_vector_type(16)));
typedef float f32x4v __attribute__((ext_vector_type(4)));
typedef unsigned int u32x4 __attribute__((ext_vector_type(4)));
typedef unsigned int u32x2 __attribute__((ext_vector_type(2)));
// may_alias variants for ALL type-punned LDS/global accesses.
typedef s16x8 s16x8_a __attribute__((may_alias));
typedef f32x4v f32x4v_a __attribute__((may_alias));
typedef u32x4 u32x4_a __attribute__((may_alias));
typedef unsigned int u32_a __attribute__((may_alias));

#if __has_builtin(__builtin_amdgcn_exp2f)
#define EXP2F(x) __builtin_amdgcn_exp2f(x)  // raw v_exp_f32, no legalization
#else
#define EXP2F(x) __builtin_exp2f(x)
#endif

__device__ __forceinline__ USH f2bf(float f) {
  union { float f; unsigned int i; } c; c.f = f;
  unsigned int x = c.i;
  return (USH)((x + 0x7FFFu + ((x >> 16) & 1u)) >> 16);
}
__device__ __forceinline__ unsigned int pk_bf16(float a, float b) {
#if __has_builtin(__builtin_amdgcn_cvt_pk_bf16_f32)
  typedef USH ush2 __attribute__((ext_vector_type(2)));
  union { ush2 v; unsigned int u; } r;
  r.v = __builtin_amdgcn_cvt_pk_bf16_f32(a, b);
  return r.u;
#else
  union { float f; unsigned int i; } ca, cb; ca.f = a; cb.f = b;
  return ((ca.i + 0x8000u) >> 16) | ((cb.i + 0x8000u) & 0xFFFF0000u);
#endif
}

__device__ __forceinline__ f32x4 mfma16(s16x8 a, s16x8 b, f32x4 c) {
  return __builtin_amdgcn_mfma_f32_16x16x32_bf16(a, b, c, 0, 0, 0);
}
__device__ __forceinline__ f32x16 mfma32(s16x8 a, s16x8 b, f32x16 c) {
  return __builtin_amdgcn_mfma_f32_32x32x16_bf16(a, b, c, 0, 0, 0);
}

// async global->LDS, 16B per lane; LDS dest semantics: wave base + lane*16.
#if __has_builtin(__builtin_amdgcn_global_load_lds)
__device__ __forceinline__ void gld_lds16(const void* g, void* l) {
  __builtin_amdgcn_global_load_lds(
      static_cast<const unsigned int __attribute__((address_space(1)))*>(
          (const void __attribute__((address_space(1)))*)g),
      static_cast<unsigned int __attribute__((address_space(3)))*>(
          (void __attribute__((address_space(3)))*)l),
      16, 0, 0);
}
#else
__device__ __forceinline__ void gld_lds16(const void* g, void* l) {
  *(s16x8_a*)l = *(const s16x8_a*)g;  // fallback: synchronous copy, same addresses
}
#endif

// ------------- prep: WT[n][k] = bf16(W[k][n]) for the 4 weight matrices -------------
__global__ __launch_bounds__(256) void prep(
    const float* __restrict__ Wq, const float* __restrict__ Wk,
    const float* __restrict__ Wv, const float* __restrict__ Wo,
    USH* __restrict__ wsT) {
  __shared__ float tile[32][33];
  const int z = blockIdx.z;
  const int t = threadIdx.x;
  const float* W = (z == 0) ? Wq : (z == 1) ? Wk : (z == 2) ? Wv : Wo;
  USH* WT = wsT + (size_t)z * 262144;
  const int n0 = blockIdx.x * 32, k0 = blockIdx.y * 32;
  const int tx = t & 31, ty = t >> 5;  // 32 x 8
  #pragma unroll
  for (int i = 0; i < 4; ++i)
    tile[ty + i * 8][tx] = W[(size_t)(k0 + ty + i * 8) * 512 + n0 + tx];
  __syncthreads();
  #pragma unroll
  for (int i = 0; i < 4; ++i)
    WT[(size_t)(n0 + ty + i * 8) * 512 + k0 + tx] = f2bf(tile[tx][ty + i * 8]);
}

// ---------------- GEMM v4: out = A[M,512] * WT^T + bias ----------------
// m97-proven single-buffer 2-barrier structure with global_load_lds staging,
// __syncthreads-only (deterministic). XOR-swizzle both-sides (rule #21).
// MODE 0: A = att bf16; out float[m*512+n] (d_out fp32).
// MODE 1: A = x fp32 staged DIRECTLY, converted to bf16 frags in-register.
template <int MODE>
__global__ __launch_bounds__(256, 3) void gemm_bias(
    const USH* __restrict__ A, const float* __restrict__ A32,
    const USH* __restrict__ BT0,
    const float* __restrict__ b0, const float* __restrict__ b1,
    const float* __restrict__ b2,
    USH* __restrict__ oQ, USH* __restrict__ oKV, float* __restrict__ oF) {
  __shared__ __align__(16) USH As[MODE == 1 ? 16384 : 8192];
  __shared__ __align__(16) USH Bs[8192];  // [128 rows][64 USH] chunk-swizzled
  const int z = blockIdx.z;
  const USH* BT = BT0 + (size_t)z * 262144;
  const float* bias = (z == 0) ? b0 : ((z == 1) ? b1 : b2);
  USH* outb = (z == 0) ? oQ : (oKV + (size_t)(z - 1) * 4194304);
  const float qs = (MODE == 1 && z == 0) ? 0.06375871528132839f : 1.0f;

  const int t = threadIdx.x;
  const int w = t >> 6, lane = t & 63;
  const int c = lane & 15, g = lane >> 4;
  const int wm = w & 1, wn = w >> 1;
  const int m0 = blockIdx.x * 128, n0 = blockIdx.y * 128;

  f32x4 acc[4][4] = {};

  const int rB = w * 32 + (lane >> 3);                       // +j*8
  const int ccB = (((lane & 7) ^ ((lane >> 3) & 7))) * 8;
  const USH* BpD = BT + (size_t)(n0 + rB) * 512 + ccB;       // +kt*64 +j*4096
  USH* lB = Bs + w * 2048 + lane * 8;                        // +j*512

  const USH* ApD = nullptr;
  USH* lA0 = nullptr;
  const float* Ap32 = nullptr;
  USH* lA1 = nullptr;
  if (MODE == 0) {
    ApD = A + (size_t)(m0 + rB) * 512 + ccB;
    lA0 = As + w * 2048 + lane * 8;
  } else {
    const int rA = w * 4 + (lane >> 4);                      // +j*16
    const int gcA = (lane & 15) ^ (rA & 15);
    Ap32 = A32 + (size_t)(m0 + rA) * 512 + gcA * 4;          // +kt*64 +j*16*512
    lA1 = As + w * 512 + lane * 8;                           // +j*2048 (USH)
  }

  for (int kt = 0; kt < 8; ++kt) {
    __syncthreads();
    if (MODE == 0) {
      #pragma unroll
      for (int j = 0; j < 4; ++j) {
        gld_lds16(ApD + kt * 64 + j * 4096, lA0 + j * 512);
        gld_lds16(BpD + kt * 64 + j * 4096, lB + j * 512);
      }
    } else {
      #pragma unroll
      for (int j = 0; j < 8; ++j)
        gld_lds16(Ap32 + kt * 64 + (size_t)j * 8192, lA1 + j * 2048);
      #pragma unroll
      for (int j = 0; j < 4; ++j)
        gld_lds16(BpD + kt * 64 + j * 4096, lB + j * 512);
    }
    __syncthreads();
    #pragma unroll
    for (int ks = 0; ks < 2; ++ks) {
      s16x8 af[4], bfr[4];
      #pragma unroll
      for (int i = 0; i < 4; ++i) {
        const int ra = wm * 64 + i * 16 + c;
        const int rb = wn * 64 + i * 16 + c;
        if (MODE == 0) {
          af[i] = *(const s16x8_a*)(As + ra * 64 + ((ks * 4 + g) ^ (ra & 7)) * 8);
        } else {
          const int e = ks * 4 + g;
          const int p0 = (2 * e) ^ (ra & 15), p1 = (2 * e + 1) ^ (ra & 15);
          const float* Af = (const float*)As + ra * 64;
          const f32x4v lo = *(const f32x4v_a*)(Af + p0 * 4);
          const f32x4v hi = *(const f32x4v_a*)(Af + p1 * 4);
          union { u32x4 u; s16x8 v; } cvt;
          cvt.u.x = pk_bf16(lo.x, lo.y); cvt.u.y = pk_bf16(lo.z, lo.w);
          cvt.u.z = pk_bf16(hi.x, hi.y); cvt.u.w = pk_bf16(hi.z, hi.w);
          af[i] = cvt.v;
        }
        bfr[i] = *(const s16x8_a*)(Bs + rb * 64 + ((ks * 4 + g) ^ (rb & 7)) * 8);
      }
      #pragma unroll
      for (int mf = 0; mf < 4; ++mf)
        #pragma unroll
        for (int nf = 0; nf < 4; ++nf)
          acc[mf][nf] = mfma16(af[mf], bfr[nf], acc[mf][nf]);
    }
  }

  #pragma unroll
  for (int nf = 0; nf < 4; ++nf) {
    const int n = n0 + wn * 64 + nf * 16 + c;
    const float bv = bias[n];
    #pragma unroll
    for (int mf = 0; mf < 4; ++mf)
      #pragma unroll
      for (int r = 0; r < 4; ++r) {
        const int m = m0 + wm * 64 + mf * 16 + g * 4 + r;
        const float v = (acc[mf][nf][r] + bv) * qs;
        if (MODE == 0) {
          oF[(size_t)m * 512 + n] = v;
        } else {
          const int bb = m >> 12, s = m & 4095, h = n >> 6, hd = n & 63;
          if (z == 2)
            outb[(((size_t)(bb * 8 + h)) * 64 + hd) * 4096 + s] = f2bf(v);
          else
            outb[(((size_t)(bb * 8 + h)) * 4096 + s) * 64 + hd] = f2bf(v);
        }
      }
  }
}

// ---------------- flash attention v16: v15 + permlane32_swap + setprio ----------------
// v15 (106.6us) post-mortem: correct (absmax identical) but regressed vs v14
// (97.4): SQ_LDS_BANK_CONFLICT DOUBLED 4.2M->8.5M. K/V read swizzles are
// bank-optimal (8 lanes/4-bank group, same multiplicity as v9's measured-zero
// pattern) -- the new contributor is the 32 __shfl_xor per iter-wave = 2.1M
// ds_bpermute on the LDS pipe contending with K/V ds_reads (~4cyc each ~=
// the 8.5M delta). v16 (T12's primitive, m255: permlane 1.20x vs bpermute):
// v_permlane32_swap_b32's TWO outputs are exactly B-frag words --
//   swap(P[4ks],P[4ks+2]) -> word0 = {lo:P[4ks], hi:X[4ks+2]},
//                            word2 = {lo:X[4ks], hi:P[4ks+2]}
// (verified against v15's passing hq-select mapping). 4 VALU instrs/SMPV
// replace 8 bpermute + 8 selects; zero LDS-pipe traffic. Plus T5 setprio(1)
// around MFMA clusters (m191: +4-7% attn; v15 has wave role-diversity),
// ds_reads hoisted ahead of the prio window.
// Structure unchanged from v15: 32x32 swapped-QK, in-register P, lane-local
// qrow, 256 thr / 4 waves, KVBLK=128 dbuf 64KB, one __syncthreads/iter,
// QK(kb+1) before SMPV(kb) ping-pong, epilogue transpose via dead Ks.
__global__ __launch_bounds__(256, 2) void attn(const USH* __restrict__ Qbuf,
                                               const USH* __restrict__ kv,
                                               USH* __restrict__ att) {
  __shared__ __align__(16) USH Ks[2 * 8192];   // [buf][128 key][64 d] swz
  __shared__ __align__(16) USH Vt[2 * 8192];   // [buf][64 hd][128 key] swz

  const int t = threadIdx.x;
  const int w = t >> 6, lane = t & 63;
  const int cq = lane & 31, hq = lane >> 5;
  // XCD-aware remap, bijective on [0,512): each XCD owns 2 bh -> KV in L2.
  const int linear = blockIdx.x + (blockIdx.y << 5);
  const int xcd = linear & 7, idx = linear >> 3;   // idx in [0,64)
  const int bh = xcd + ((idx >> 5) << 3);
  const int bb = bh >> 3, hh = bh & 7;
  const size_t base = (size_t)bh * 262144;  // 4096*64
  const USH* Q = Qbuf + base;
  const USH* K = kv + base;                 // [S,Hd]
  const USH* V = kv + 4194304 + base;       // [Hd,S] (pre-transposed)
  const int q0 = (idx & 31) * 128 + w * 32;

  // Q fragments: B-operand of S^T = K*Q^T. B[k = t4*16 + hq*8 + j][n = cq]
  s16x8 qB[4];
  #pragma unroll
  for (int t4 = 0; t4 < 4; ++t4)
    qB[t4] = *(const s16x8_a*)(Q + (size_t)(q0 + cq) * 64 + t4 * 16 + hq * 8);

  // all-ones A-fragment for l = sum_key P (every D row = l[qrow])
  s16x8 ones;
  #pragma unroll
  for (int j = 0; j < 8; ++j) ones[j] = (short)0x3F80;

  f32x16 o[2] = {};   // O^T[hd(hb,r,hq)][qrow=cq], hb = hd/32
  f32x16 ol = {};     // l in every reg; use [0]

  // --- DMA lane mappings (4 waves, 4 calls each per K and V per tile) ---
  const int rK = t >> 3;
  const USH* gK0 = K + (size_t)rK * 64 + (((t & 7) ^ (rK & 7)) * 8);  // +kt*8192 +j*2048
  const int rV = t >> 4;
  const USH* gV0 = V + (size_t)rV * 4096 + (((t & 15) ^ (rV & 7)) * 8); // +kt*128 +j*65536
  USH* lK = Ks + t * 8;   // +buf +j*2048
  USH* lV = Vt + t * 8;   // +buf +j*2048

  auto DMA = [&](int kt, int buf) {
    #pragma unroll
    for (int j = 0; j < 4; ++j) {
      gld_lds16(gK0 + (size_t)kt * 8192 + j * 2048, lK + buf + j * 2048);
      gld_lds16(gV0 + (size_t)kt * 128 + (size_t)j * 65536, lV + buf + j * 2048);
    }
  };

  // S^T[key 32][qrow 32] for key-block kb: loads batched, then prio'd MFMA chain.
  auto QK = [&](int kb, int buf) -> f32x16 {
    s16x8 ka[4];
    #pragma unroll
    for (int t4 = 0; t4 < 4; ++t4)
      ka[t4] = *(const s16x8_a*)(
          Ks + buf + (kb * 32 + cq) * 64 + (((2 * t4 + hq) ^ (cq & 7)) * 8));
    f32x16 st = {};
    __builtin_amdgcn_s_setprio(1);
    #pragma unroll
    for (int t4 = 0; t4 < 4; ++t4) st = mfma32(ka[t4], qB[t4], st);
    __builtin_amdgcn_s_setprio(0);
    return st;
  };

  // exp2 + pack + permlane32_swap + PV + l for key-block kb.
  auto SMPV = [&](f32x16 st, int kb, int buf) {
    unsigned int P[8];
    #pragma unroll
    for (int i = 0; i < 8; ++i)
      P[i] = pk_bf16(EXP2F(st[2 * i]), EXP2F(st[2 * i + 1]));
    #pragma unroll
    for (int ks = 0; ks < 2; ++ks) {
      s16x8 bks;
#if __has_builtin(__builtin_amdgcn_permlane32_swap)
      const u32x2 r02 =
          __builtin_amdgcn_permlane32_swap(P[4 * ks], P[4 * ks + 2], false, false);
      const u32x2 r13 =
          __builtin_amdgcn_permlane32_swap(P[4 * ks + 1], P[4 * ks + 3], false, false);
      union { u32x4 u; s16x8 v; } bfu;
      bfu.u.x = r02[0]; bfu.u.y = r13[0]; bfu.u.z = r02[1]; bfu.u.w = r13[1];
      bks = bfu.v;
#else
      unsigned int X0 = __shfl_xor(P[4 * ks], 32), X1 = __shfl_xor(P[4 * ks + 1], 32);
      unsigned int X2 = __shfl_xor(P[4 * ks + 2], 32), X3 = __shfl_xor(P[4 * ks + 3], 32);
      union { u32x4 u; s16x8 v; } bfu;
      bfu.u.x = hq ? X2 : P[4 * ks];
      bfu.u.y = hq ? X3 : P[4 * ks + 1];
      bfu.u.z = hq ? P[4 * ks + 2] : X0;
      bfu.u.w = hq ? P[4 * ks + 3] : X1;
      bks = bfu.v;
#endif
      s16x8 va[2];
      #pragma unroll
      for (int hb = 0; hb < 2; ++hb)
        va[hb] = *(const s16x8_a*)(
            Vt + buf + (hb * 32 + cq) * 128 +
            (((4 * kb + 2 * ks + hq) ^ (cq & 7)) * 8));
      __builtin_amdgcn_s_setprio(1);
      o[0] = mfma32(va[0], bks, o[0]);
      o[1] = mfma32(va[1], bks, o[1]);
      ol = mfma32(ones, bks, ol);
      __builtin_amdgcn_s_setprio(0);
    }
  };

  // prologue: tile 0 -> buf 0
  DMA(0, 0);

  for (int kt = 0; kt < 32; ++kt) {
    const int buf = (kt & 1) * 8192;
    __syncthreads();  // implicit vmcnt(0): tile kt resident; buf^1 free
    if (kt < 31) DMA(kt + 1, buf ^ 8192);
    // in-iter pipeline: QK one key-block ahead of softmax+PV
    f32x16 stA = QK(0, buf);
    f32x16 stB = QK(1, buf);
    SMPV(stA, 0, buf);
    stA = QK(2, buf);
    SMPV(stB, 1, buf);
    stB = QK(3, buf);
    SMPV(stA, 2, buf);
    SMPV(stB, 3, buf);
  }

  // ---- epilogue: divide by l, transpose via dead Ks, coalesced store ----
  __syncthreads();  // all waves done with Ks/Vt
  USH* scr = Ks + w * 2304;  // per-wave [32 qrow][72 USH pad] (4608 B, 16B-aligned)
  const float linv = 1.0f / ol[0];
  #pragma unroll
  for (int hb = 0; hb < 2; ++hb)
    #pragma unroll
    for (int i = 0; i < 8; ++i) {
      const int hd = hb * 32 + 4 * hq + 2 * (i & 1) + 8 * (i >> 1);
      const unsigned int pw =
          pk_bf16(o[hb][2 * i] * linv, o[hb][2 * i + 1] * linv);
      *(u32_a*)(scr + cq * 72 + hd) = pw;
    }
  // wave-local in-order DS: no barrier needed before read-back
  #pragma unroll
  for (int p = 0; p < 4; ++p) {
    const int row = p * 8 + (lane >> 3), col = (lane & 7) * 8;
    const s16x8 v = *(const s16x8_a*)(scr + row * 72 + col);
    *(s16x8_a*)(att + ((size_t)(bb * 4096 + q0 + row)) * 512 + hh * 64 + col) = v;
  }
}

extern "C" void kernel_launch(void* const* d_in, const int* in_sizes, int n_in,
                              void* d_out, int out_size, void* d_ws, size_t ws_size,
                              hipStream_t stream) {
  (void)in_sizes; (void)n_in; (void)out_size; (void)ws_size;
  const float* x  = (const float*)d_in[0];
  const float* Wq = (const float*)d_in[1];
  const float* bq = (const float*)d_in[2];
  const float* Wk = (const float*)d_in[3];
  const float* bk = (const float*)d_in[4];
  const float* Wv = (const float*)d_in[5];
  const float* bv = (const float*)d_in[6];
  const float* Wo = (const float*)d_in[7];
  const float* bo = (const float*)d_in[8];
  USH* ws  = (USH*)d_ws;
  USH* wT  = ws;                       // 4 * 262144 bf16 transposed weights (2 MB)
  USH* kv  = ws + 1048576;             // K [B,H,S,Hd] + V [B,H,Hd,S] bf16 (16 MB)
  USH* att = ws + 1048576 + 8388608;   // 4194304 : attn out [B,S,D] bf16 (8 MB)
  float* outF = (float*)d_out;         // fp32 output (16 MB)
  USH* qscratch = (USH*)d_out;         // Q bf16 (8 MB), dead before final GEMM

  prep<<<dim3(16, 16, 4), 256, 0, stream>>>(Wq, Wk, Wv, Wo, wT);
  gemm_bias<1><<<dim3(64, 4, 3), 256, 0, stream>>>(nullptr, x, wT, bq, bk, bv,
                                                   qscratch, kv, nullptr);
  attn<<<dim3(32, 16), 256, 0, stream>>>(qscratch, kv, att);
  gemm_bias<0><<<dim3(64, 4, 1), 256, 0, stream>>>(att, nullptr, wT + 3 * 262144,
                                                   bo, bo, bo,
                                                   nullptr, nullptr, outF);
}

// Round 12
// 205.263 us; speedup vs baseline: 1.0336x; 1.0158x over previous
//
#include <hip/hip_runtime.h>

typedef unsigned short USH;
typedef short s16x8 __attribute__((ext_vector_type(8)));
typedef float f32x4 __attribute__((ext_vector_type(4)));
typedef float f32x4v __attribute__((ext_vector_type(4)));
typedef unsigned int u32x4 __attribute__((ext_vector_type(4)));
// may_alias variants for ALL type-punned LDS/global accesses.
typedef s16x8 s16x8_a __attribute__((may_alias));
typedef f32x4v f32x4v_a __attribute__((may_alias));
typedef u32x4 u32x4_a __attribute__((may_alias));
typedef unsigned long long u64_a __attribute__((may_alias));

#if __has_builtin(__builtin_amdgcn_exp2f)
#define EXP2F(x) __builtin_amdgcn_exp2f(x)  // raw v_exp_f32, no legalization
#else
#define EXP2F(x) __builtin_exp2f(x)
#endif

__device__ __forceinline__ USH f2bf(float f) {
  union { float f; unsigned int i; } c; c.f = f;
  unsigned int x = c.i;
  return (USH)((x + 0x7FFFu + ((x >> 16) & 1u)) >> 16);
}
__device__ __forceinline__ unsigned int pk_bf16(float a, float b) {
#if __has_builtin(__builtin_amdgcn_cvt_pk_bf16_f32)
  typedef USH ush2 __attribute__((ext_vector_type(2)));
  union { ush2 v; unsigned int u; } r;
  r.v = __builtin_amdgcn_cvt_pk_bf16_f32(a, b);
  return r.u;
#else
  union { float f; unsigned int i; } ca, cb; ca.f = a; cb.f = b;
  return ((ca.i + 0x8000u) >> 16) | ((cb.i + 0x8000u) & 0xFFFF0000u);
#endif
}

__device__ __forceinline__ f32x4 mfma16(s16x8 a, s16x8 b, f32x4 c) {
  return __builtin_amdgcn_mfma_f32_16x16x32_bf16(a, b, c, 0, 0, 0);
}

// async global->LDS, 16B per lane; LDS dest semantics: wave base + lane*16.
#if __has_builtin(__builtin_amdgcn_global_load_lds)
__device__ __forceinline__ void gld_lds16(const void* g, void* l) {
  __builtin_amdgcn_global_load_lds(
      static_cast<const unsigned int __attribute__((address_space(1)))*>(
          (const void __attribute__((address_space(1)))*)g),
      static_cast<unsigned int __attribute__((address_space(3)))*>(
          (void __attribute__((address_space(3)))*)l),
      16, 0, 0);
}
#else
__device__ __forceinline__ void gld_lds16(const void* g, void* l) {
  *(s16x8_a*)l = *(const s16x8_a*)g;  // fallback: synchronous copy, same addresses
}
#endif

// ------------- prep: WT[n][k] = bf16(W[k][n]) for the 4 weight matrices -------------
__global__ __launch_bounds__(256) void prep(
    const float* __restrict__ Wq, const float* __restrict__ Wk,
    const float* __restrict__ Wv, const float* __restrict__ Wo,
    USH* __restrict__ wsT) {
  __shared__ float tile[32][33];
  const int z = blockIdx.z;
  const int t = threadIdx.x;
  const float* W = (z == 0) ? Wq : (z == 1) ? Wk : (z == 2) ? Wv : Wo;
  USH* WT = wsT + (size_t)z * 262144;
  const int n0 = blockIdx.x * 32, k0 = blockIdx.y * 32;
  const int tx = t & 31, ty = t >> 5;  // 32 x 8
  #pragma unroll
  for (int i = 0; i < 4; ++i)
    tile[ty + i * 8][tx] = W[(size_t)(k0 + ty + i * 8) * 512 + n0 + tx];
  __syncthreads();
  #pragma unroll
  for (int i = 0; i < 4; ++i)
    WT[(size_t)(n0 + ty + i * 8) * 512 + k0 + tx] = f2bf(tile[tx][ty + i * 8]);
}

// ---------------- GEMM v4: out = A[M,512] * WT^T + bias ----------------
// m97-proven single-buffer 2-barrier structure with global_load_lds staging,
// __syncthreads-only (deterministic). XOR-swizzle both-sides (rule #21).
// MODE 0: A = att bf16; out float[m*512+n] (d_out fp32).
// MODE 1: A = x fp32 staged DIRECTLY, converted to bf16 frags in-register.
template <int MODE>
__global__ __launch_bounds__(256, 3) void gemm_bias(
    const USH* __restrict__ A, const float* __restrict__ A32,
    const USH* __restrict__ BT0,
    const float* __restrict__ b0, const float* __restrict__ b1,
    const float* __restrict__ b2,
    USH* __restrict__ oQ, USH* __restrict__ oKV, float* __restrict__ oF) {
  __shared__ __align__(16) USH As[MODE == 1 ? 16384 : 8192];
  __shared__ __align__(16) USH Bs[8192];  // [128 rows][64 USH] chunk-swizzled
  const int z = blockIdx.z;
  const USH* BT = BT0 + (size_t)z * 262144;
  const float* bias = (z == 0) ? b0 : ((z == 1) ? b1 : b2);
  USH* outb = (z == 0) ? oQ : (oKV + (size_t)(z - 1) * 4194304);
  const float qs = (MODE == 1 && z == 0) ? 0.06375871528132839f : 1.0f;

  const int t = threadIdx.x;
  const int w = t >> 6, lane = t & 63;
  const int c = lane & 15, g = lane >> 4;
  const int wm = w & 1, wn = w >> 1;
  const int m0 = blockIdx.x * 128, n0 = blockIdx.y * 128;

  f32x4 acc[4][4] = {};

  const int rB = w * 32 + (lane >> 3);                       // +j*8
  const int ccB = (((lane & 7) ^ ((lane >> 3) & 7))) * 8;
  const USH* BpD = BT + (size_t)(n0 + rB) * 512 + ccB;       // +kt*64 +j*4096
  USH* lB = Bs + w * 2048 + lane * 8;                        // +j*512

  const USH* ApD = nullptr;
  USH* lA0 = nullptr;
  const float* Ap32 = nullptr;
  USH* lA1 = nullptr;
  if (MODE == 0) {
    ApD = A + (size_t)(m0 + rB) * 512 + ccB;
    lA0 = As + w * 2048 + lane * 8;
  } else {
    const int rA = w * 4 + (lane >> 4);                      // +j*16
    const int gcA = (lane & 15) ^ (rA & 15);
    Ap32 = A32 + (size_t)(m0 + rA) * 512 + gcA * 4;          // +kt*64 +j*16*512
    lA1 = As + w * 512 + lane * 8;                           // +j*2048 (USH)
  }

  for (int kt = 0; kt < 8; ++kt) {
    __syncthreads();
    if (MODE == 0) {
      #pragma unroll
      for (int j = 0; j < 4; ++j) {
        gld_lds16(ApD + kt * 64 + j * 4096, lA0 + j * 512);
        gld_lds16(BpD + kt * 64 + j * 4096, lB + j * 512);
      }
    } else {
      #pragma unroll
      for (int j = 0; j < 8; ++j)
        gld_lds16(Ap32 + kt * 64 + (size_t)j * 8192, lA1 + j * 2048);
      #pragma unroll
      for (int j = 0; j < 4; ++j)
        gld_lds16(BpD + kt * 64 + j * 4096, lB + j * 512);
    }
    __syncthreads();
    #pragma unroll
    for (int ks = 0; ks < 2; ++ks) {
      s16x8 af[4], bfr[4];
      #pragma unroll
      for (int i = 0; i < 4; ++i) {
        const int ra = wm * 64 + i * 16 + c;
        const int rb = wn * 64 + i * 16 + c;
        if (MODE == 0) {
          af[i] = *(const s16x8_a*)(As + ra * 64 + ((ks * 4 + g) ^ (ra & 7)) * 8);
        } else {
          const int e = ks * 4 + g;
          const int p0 = (2 * e) ^ (ra & 15), p1 = (2 * e + 1) ^ (ra & 15);
          const float* Af = (const float*)As + ra * 64;
          const f32x4v lo = *(const f32x4v_a*)(Af + p0 * 4);
          const f32x4v hi = *(const f32x4v_a*)(Af + p1 * 4);
          union { u32x4 u; s16x8 v; } cvt;
          cvt.u.x = pk_bf16(lo.x, lo.y); cvt.u.y = pk_bf16(lo.z, lo.w);
          cvt.u.z = pk_bf16(hi.x, hi.y); cvt.u.w = pk_bf16(hi.z, hi.w);
          af[i] = cvt.v;
        }
        bfr[i] = *(const s16x8_a*)(Bs + rb * 64 + ((ks * 4 + g) ^ (rb & 7)) * 8);
      }
      #pragma unroll
      for (int mf = 0; mf < 4; ++mf)
        #pragma unroll
        for (int nf = 0; nf < 4; ++nf)
          acc[mf][nf] = mfma16(af[mf], bfr[nf], acc[mf][nf]);
    }
  }

  #pragma unroll
  for (int nf = 0; nf < 4; ++nf) {
    const int n = n0 + wn * 64 + nf * 16 + c;
    const float bv = bias[n];
    #pragma unroll
    for (int mf = 0; mf < 4; ++mf)
      #pragma unroll
      for (int r = 0; r < 4; ++r) {
        const int m = m0 + wm * 64 + mf * 16 + g * 4 + r;
        const float v = (acc[mf][nf][r] + bv) * qs;
        if (MODE == 0) {
          oF[(size_t)m * 512 + n] = v;
        } else {
          const int bb = m >> 12, s = m & 4095, h = n >> 6, hd = n & 63;
          if (z == 2)
            outb[(((size_t)(bb * 8 + h)) * 64 + hd) * 4096 + s] = f2bf(v);
          else
            outb[(((size_t)(bb * 8 + h)) * 4096 + s) * 64 + hd] = f2bf(v);
        }
      }
  }
}

// ---------------- flash attention v17: v14 (proven 97.4us) + T5 setprio ----------------
// v15/v16 32x32 excursion post-mortem: correct but slower (103.9-106.6);
// SQ_LDS_BANK_CONFLICT identical (8,486,912) after shfl->permlane swap
// (VGPR 116->88 proves permlane compiled) -> conflicts are deterministic
// K/V ds_read collisions in that structure's ^(cq&7) swizzle, NOT bpermute;
// line abandoned (even conflict-free it only reaches v14 parity). Residue:
// setprio helped (+2.7us on v16; m191 +4-7%). v17 = v14 + setprio(1) around
// QK and PV MFMA clusters, ds_reads batched ahead of each prio window.
// v14 structure: 512 thr / 8 waves x 32 q-rows; grid (16 qt, 16 bh) = 256
// blocks = 1/CU; KVBLK=128 dbuf; LDS 135 KB; XOR-swizzled K/V (measured-
// near-zero-conflict family); Ps wave-local; l = P.1 on MFMA pipe; Q
// pre-scaled by sc*log2e; one __syncthreads per iter (deterministic).
__global__ __launch_bounds__(512, 2) void attn(const USH* __restrict__ Qbuf,
                                               const USH* __restrict__ kv,
                                               USH* __restrict__ att) {
  __shared__ __align__(16) USH Ks[2 * 8192];    // [buf][half][key 0..127][32 USH]
  __shared__ __align__(16) USH Vt[2 * 8192];    // [buf][64 hd][128 USH]
  __shared__ __align__(16) USH Ps[8][32 * 140]; // per-wave [32 qrow][140 key-pad]
  __shared__ float lbuf[8][32];

  const int t = threadIdx.x;
  const int w = t >> 6, lane = t & 63;
  const int c = lane & 15, g = lane >> 4;
  // XCD-aware remap, bijective on [0,256): each XCD owns bh {xcd, xcd+8}
  // -> KV working set 2 MB <= per-XCD L2.
  const int linear = blockIdx.x + (blockIdx.y << 4);
  const int xcd = linear & 7, idx = linear >> 3;   // idx in [0,32)
  const int bh = xcd + ((idx >> 4) << 3);
  const int bb = bh >> 3, hh = bh & 7;
  const size_t base = (size_t)bh * 262144;  // 4096*64
  const USH* Q = Qbuf + base;
  const USH* K = kv + base;                 // [S,Hd]
  const USH* V = kv + 4194304 + base;       // [Hd,S] (pre-transposed)
  const int q0 = (idx & 15) * 256 + w * 32;

  // Q fragments (B-operand of S^T): registers for the whole K loop
  s16x8 qf[2][2];  // [qi][kh]
  #pragma unroll
  for (int qi = 0; qi < 2; ++qi)
    #pragma unroll
    for (int kh = 0; kh < 2; ++kh)
      qf[qi][kh] = *(const s16x8_a*)(Q + (size_t)(q0 + qi * 16 + c) * 64 + kh * 32 + g * 8);

  // constant ones-column B-fragment: l = P . 1 on the MFMA pipe
  s16x8 onesf;
  {
    const short one = (short)0x3F80, val = (c == 0) ? one : (short)0;
    #pragma unroll
    for (int j = 0; j < 8; ++j) onesf[j] = val;
  }

  f32x4 o[2][4] = {};
  f32x4 o_l[2] = {};

  // --- DMA lane mappings (8 waves, 2 calls each per K and V per tile) ---
  const int keyK = w * 16 + (lane >> 2);               // 0..127
  const int ccK = (lane & 3) ^ ((keyK >> 1) & 3);
  const USH* gK0 = K + (size_t)keyK * 64 + ccK * 8;    // +kt*8192 +j*32
  const int hdV = w * 4 + (lane >> 4);                 // 0..31, +j*32
  const int ccV = (lane & 15) ^ (hdV & 7);
  const USH* gV0 = V + (size_t)hdV * 4096 + ccV * 8;   // +kt*128 +j*131072
  USH* lK = Ks + w * 512 + lane * 8;   // +buf*8192 +j*4096
  USH* lV = Vt + w * 512 + lane * 8;   // +buf*8192 +j*4096

  // issue tile 0 -> buf 0
  #pragma unroll
  for (int j = 0; j < 2; ++j) {
    gld_lds16(gK0 + j * 32, lK + j * 4096);
    gld_lds16(gV0 + (size_t)j * 131072, lV + j * 4096);
  }

  for (int kt = 0; kt < 32; ++kt) {
    const int buf = kt & 1;
    __syncthreads();  // implicit vmcnt(0): tile kt resident; buf^1 free
    if (kt < 31) {    // issue tile kt+1 -> buf^1; flies across this iteration
      const int nb = (buf ^ 1) * 8192;
      #pragma unroll
      for (int j = 0; j < 2; ++j) {
        gld_lds16(gK0 + (size_t)(kt + 1) * 8192 + j * 32, lK + nb + j * 4096);
        gld_lds16(gV0 + (size_t)(kt + 1) * 128 + (size_t)j * 131072, lV + nb + j * 4096);
      }
    }

    // S^T[key][qrow] = K * Q^T  (Q pre-scaled; st IS the exp2 argument)
    f32x4 st[2][8] = {};
    #pragma unroll
    for (int kh = 0; kh < 2; ++kh) {
      s16x8 ak[8];
      #pragma unroll
      for (int kff = 0; kff < 8; ++kff) {
        const int row = kff * 16 + c;
        const int qsw = (g ^ ((c >> 1) & 3)) * 8;
        ak[kff] = *(const s16x8_a*)(Ks + buf * 8192 + kh * 4096 + row * 32 + qsw);
      }
      __builtin_amdgcn_s_setprio(1);
      #pragma unroll
      for (int qi = 0; qi < 2; ++qi)
        #pragma unroll
        for (int kff = 0; kff < 8; ++kff)
          st[qi][kff] = mfma16(ak[kff], qf[qi][kh], st[qi][kff]);
      __builtin_amdgcn_s_setprio(0);
    }

    // p = exp2(s); pack; write P to Ps[w] (wave-local; in-order DS)
    #pragma unroll
    for (int qi = 0; qi < 2; ++qi)
      #pragma unroll
      for (int kff = 0; kff < 8; ++kff) {
        #pragma unroll
        for (int r = 0; r < 4; ++r) st[qi][kff][r] = EXP2F(st[qi][kff][r]);
        const unsigned int lo = pk_bf16(st[qi][kff][0], st[qi][kff][1]);
        const unsigned int hi = pk_bf16(st[qi][kff][2], st[qi][kff][3]);
        *(u64_a*)(&Ps[w][(qi * 16 + c) * 140 + kff * 16 + g * 4]) =
            (unsigned long long)lo | ((unsigned long long)hi << 32);
      }

    // O[qrow][hd] += P * V ; l[qrow] += P . 1
    #pragma unroll
    for (int kf = 0; kf < 4; ++kf) {
      s16x8 ap[2];
      #pragma unroll
      for (int qi = 0; qi < 2; ++qi)
        ap[qi] = *(const s16x8_a*)(&Ps[w][(qi * 16 + c) * 140 + kf * 32 + g * 8]);
      s16x8 bv[4];
      #pragma unroll
      for (int hf = 0; hf < 4; ++hf) {
        const int qv = (((kf * 4 + g) ^ (c & 7))) * 8;
        bv[hf] = *(const s16x8_a*)(Vt + buf * 8192 + (c + 16 * hf) * 128 + qv);
      }
      __builtin_amdgcn_s_setprio(1);
      #pragma unroll
      for (int qi = 0; qi < 2; ++qi) {
        #pragma unroll
        for (int hf = 0; hf < 4; ++hf)
          o[qi][hf] = mfma16(ap[qi], bv[hf], o[qi][hf]);
        o_l[qi] = mfma16(ap[qi], onesf, o_l[qi]);
      }
      __builtin_amdgcn_s_setprio(0);
    }
  }

  // l lives in lanes c==0 (D[m][0]); broadcast within the wave via LDS
  if (c == 0) {
    #pragma unroll
    for (int qi = 0; qi < 2; ++qi)
      #pragma unroll
      for (int r = 0; r < 4; ++r) lbuf[w][qi * 16 + g * 4 + r] = o_l[qi][r];
  }
  __syncthreads();

  #pragma unroll
  for (int qi = 0; qi < 2; ++qi)
    #pragma unroll
    for (int r = 0; r < 4; ++r) {
      const int ml = qi * 16 + g * 4 + r;
      const float linv = 1.0f / lbuf[w][ml];
      const int qrow = q0 + ml;
      #pragma unroll
      for (int hf = 0; hf < 4; ++hf) {
        const int hd = c + 16 * hf;
        att[((size_t)(bb * 4096 + qrow)) * 512 + hh * 64 + hd] =
            f2bf(o[qi][hf][r] * linv);
      }
    }
}

extern "C" void kernel_launch(void* const* d_in, const int* in_sizes, int n_in,
                              void* d_out, int out_size, void* d_ws, size_t ws_size,
                              hipStream_t stream) {
  (void)in_sizes; (void)n_in; (void)out_size; (void)ws_size;
  const float* x  = (const float*)d_in[0];
  const float* Wq = (const float*)d_in[1];
  const float* bq = (const float*)d_in[2];
  const float* Wk = (const float*)d_in[3];
  const float* bk = (const float*)d_in[4];
  const float* Wv = (const float*)d_in[5];
  const float* bv = (const float*)d_in[6];
  const float* Wo = (const float*)d_in[7];
  const float* bo = (const float*)d_in[8];
  USH* ws  = (USH*)d_ws;
  USH* wT  = ws;                       // 4 * 262144 bf16 transposed weights (2 MB)
  USH* kv  = ws + 1048576;             // K [B,H,S,Hd] + V [B,H,Hd,S] bf16 (16 MB)
  USH* att = ws + 1048576 + 8388608;   // 4194304 : attn out [B,S,D] bf16 (8 MB)
  float* outF = (float*)d_out;         // fp32 output (16 MB)
  USH* qscratch = (USH*)d_out;         // Q bf16 (8 MB), dead before final GEMM

  prep<<<dim3(16, 16, 4), 256, 0, stream>>>(Wq, Wk, Wv, Wo, wT);
  gemm_bias<1><<<dim3(64, 4, 3), 256, 0, stream>>>(nullptr, x, wT, bq, bk, bv,
                                                   qscratch, kv, nullptr);
  attn<<<dim3(16, 16), 512, 0, stream>>>(qscratch, kv, att);
  gemm_bias<0><<<dim3(64, 4, 1), 256, 0, stream>>>(att, nullptr, wT + 3 * 262144,
                                                   bo, bo, bo,
                                                   nullptr, nullptr, outF);
}

// Round 13
// 204.724 us; speedup vs baseline: 1.0363x; 1.0026x over previous
//
#include <hip/hip_runtime.h>

typedef unsigned short USH;
typedef short s16x8 __attribute__((ext_vector_type(8)));
typedef float f32x4 __attribute__((ext_vector_type(4)));
typedef float f32x4v __attribute__((ext_vector_type(4)));
typedef unsigned int u32x4 __attribute__((ext_vector_type(4)));
// may_alias variants for ALL type-punned LDS/global accesses.
typedef s16x8 s16x8_a __attribute__((may_alias));
typedef f32x4v f32x4v_a __attribute__((may_alias));
typedef u32x4 u32x4_a __attribute__((may_alias));
typedef unsigned long long u64_a __attribute__((may_alias));

#if __has_builtin(__builtin_amdgcn_exp2f)
#define EXP2F(x) __builtin_amdgcn_exp2f(x)  // raw v_exp_f32, no legalization
#else
#define EXP2F(x) __builtin_exp2f(x)
#endif

__device__ __forceinline__ USH f2bf(float f) {
  union { float f; unsigned int i; } c; c.f = f;
  unsigned int x = c.i;
  return (USH)((x + 0x7FFFu + ((x >> 16) & 1u)) >> 16);
}
__device__ __forceinline__ unsigned int pk_bf16(float a, float b) {
#if __has_builtin(__builtin_amdgcn_cvt_pk_bf16_f32)
  typedef USH ush2 __attribute__((ext_vector_type(2)));
  union { ush2 v; unsigned int u; } r;
  r.v = __builtin_amdgcn_cvt_pk_bf16_f32(a, b);
  return r.u;
#else
  union { float f; unsigned int i; } ca, cb; ca.f = a; cb.f = b;
  return ((ca.i + 0x8000u) >> 16) | ((cb.i + 0x8000u) & 0xFFFF0000u);
#endif
}

__device__ __forceinline__ f32x4 mfma16(s16x8 a, s16x8 b, f32x4 c) {
  return __builtin_amdgcn_mfma_f32_16x16x32_bf16(a, b, c, 0, 0, 0);
}

// async global->LDS, 16B per lane; LDS dest semantics: wave base + lane*16.
#if __has_builtin(__builtin_amdgcn_global_load_lds)
__device__ __forceinline__ void gld_lds16(const void* g, void* l) {
  __builtin_amdgcn_global_load_lds(
      static_cast<const unsigned int __attribute__((address_space(1)))*>(
          (const void __attribute__((address_space(1)))*)g),
      static_cast<unsigned int __attribute__((address_space(3)))*>(
          (void __attribute__((address_space(3)))*)l),
      16, 0, 0);
}
#else
__device__ __forceinline__ void gld_lds16(const void* g, void* l) {
  *(s16x8_a*)l = *(const s16x8_a*)g;  // fallback: synchronous copy, same addresses
}
#endif

// ------------- prep: WT[n][k] = bf16(W[k][n]) for the 4 weight matrices -------------
// (x fp32->bf16 conversion is fused into gemm_bias MODE 1: byte motion
//  identical, one fewer dispatch, one fewer 96 MB pass.)
__global__ __launch_bounds__(256) void prep(
    const float* __restrict__ Wq, const float* __restrict__ Wk,
    const float* __restrict__ Wv, const float* __restrict__ Wo,
    USH* __restrict__ wsT) {
  __shared__ float tile[32][33];
  const int z = blockIdx.z;
  const int t = threadIdx.x;
  const float* W = (z == 0) ? Wq : (z == 1) ? Wk : (z == 2) ? Wv : Wo;
  USH* WT = wsT + (size_t)z * 262144;
  const int n0 = blockIdx.x * 32, k0 = blockIdx.y * 32;
  const int tx = t & 31, ty = t >> 5;  // 32 x 8
  #pragma unroll
  for (int i = 0; i < 4; ++i)
    tile[ty + i * 8][tx] = W[(size_t)(k0 + ty + i * 8) * 512 + n0 + tx];
  __syncthreads();
  #pragma unroll
  for (int i = 0; i < 4; ++i)
    WT[(size_t)(n0 + ty + i * 8) * 512 + k0 + tx] = f2bf(tile[tx][ty + i * 8]);
}

// ---------------- GEMM v4: out = A[M,512] * WT^T + bias ----------------
// FINAL. m97-proven single-buffer 2-barrier structure with global_load_lds
// staging, __syncthreads-only (deterministic; tripwire-verified r6). XOR-
// swizzle both-sides (rule #21). Counted-vmcnt ring variant raced (r5
// tripwire) -- do not reintroduce without a multi-run race screen.
// MODE 0: A = att bf16; out float[m*512+n] (d_out fp32).
// MODE 1: A = x fp32 staged DIRECTLY, converted to bf16 frags in-register
//   (bit-identical rounding to the old prep pass).
template <int MODE>
__global__ __launch_bounds__(256, 3) void gemm_bias(
    const USH* __restrict__ A, const float* __restrict__ A32,
    const USH* __restrict__ BT0,
    const float* __restrict__ b0, const float* __restrict__ b1,
    const float* __restrict__ b2,
    USH* __restrict__ oQ, USH* __restrict__ oKV, float* __restrict__ oF) {
  __shared__ __align__(16) USH As[MODE == 1 ? 16384 : 8192];
  __shared__ __align__(16) USH Bs[8192];  // [128 rows][64 USH] chunk-swizzled
  const int z = blockIdx.z;
  const USH* BT = BT0 + (size_t)z * 262144;
  const float* bias = (z == 0) ? b0 : ((z == 1) ? b1 : b2);
  USH* outb = (z == 0) ? oQ : (oKV + (size_t)(z - 1) * 4194304);
  const float qs = (MODE == 1 && z == 0) ? 0.06375871528132839f : 1.0f;

  const int t = threadIdx.x;
  const int w = t >> 6, lane = t & 63;
  const int c = lane & 15, g = lane >> 4;
  const int wm = w & 1, wn = w >> 1;
  const int m0 = blockIdx.x * 128, n0 = blockIdx.y * 128;

  f32x4 acc[4][4] = {};

  const int rB = w * 32 + (lane >> 3);                       // +j*8
  const int ccB = (((lane & 7) ^ ((lane >> 3) & 7))) * 8;
  const USH* BpD = BT + (size_t)(n0 + rB) * 512 + ccB;       // +kt*64 +j*4096
  USH* lB = Bs + w * 2048 + lane * 8;                        // +j*512

  const USH* ApD = nullptr;
  USH* lA0 = nullptr;
  const float* Ap32 = nullptr;
  USH* lA1 = nullptr;
  if (MODE == 0) {
    ApD = A + (size_t)(m0 + rB) * 512 + ccB;
    lA0 = As + w * 2048 + lane * 8;
  } else {
    const int rA = w * 4 + (lane >> 4);                      // +j*16
    const int gcA = (lane & 15) ^ (rA & 15);
    Ap32 = A32 + (size_t)(m0 + rA) * 512 + gcA * 4;          // +kt*64 +j*16*512
    lA1 = As + w * 512 + lane * 8;                           // +j*2048 (USH)
  }

  for (int kt = 0; kt < 8; ++kt) {
    __syncthreads();
    if (MODE == 0) {
      #pragma unroll
      for (int j = 0; j < 4; ++j) {
        gld_lds16(ApD + kt * 64 + j * 4096, lA0 + j * 512);
        gld_lds16(BpD + kt * 64 + j * 4096, lB + j * 512);
      }
    } else {
      #pragma unroll
      for (int j = 0; j < 8; ++j)
        gld_lds16(Ap32 + kt * 64 + (size_t)j * 8192, lA1 + j * 2048);
      #pragma unroll
      for (int j = 0; j < 4; ++j)
        gld_lds16(BpD + kt * 64 + j * 4096, lB + j * 512);
    }
    __syncthreads();
    #pragma unroll
    for (int ks = 0; ks < 2; ++ks) {
      s16x8 af[4], bfr[4];
      #pragma unroll
      for (int i = 0; i < 4; ++i) {
        const int ra = wm * 64 + i * 16 + c;
        const int rb = wn * 64 + i * 16 + c;
        if (MODE == 0) {
          af[i] = *(const s16x8_a*)(As + ra * 64 + ((ks * 4 + g) ^ (ra & 7)) * 8);
        } else {
          const int e = ks * 4 + g;
          const int p0 = (2 * e) ^ (ra & 15), p1 = (2 * e + 1) ^ (ra & 15);
          const float* Af = (const float*)As + ra * 64;
          const f32x4v lo = *(const f32x4v_a*)(Af + p0 * 4);
          const f32x4v hi = *(const f32x4v_a*)(Af + p1 * 4);
          union { u32x4 u; s16x8 v; } cvt;
          cvt.u.x = pk_bf16(lo.x, lo.y); cvt.u.y = pk_bf16(lo.z, lo.w);
          cvt.u.z = pk_bf16(hi.x, hi.y); cvt.u.w = pk_bf16(hi.z, hi.w);
          af[i] = cvt.v;
        }
        bfr[i] = *(const s16x8_a*)(Bs + rb * 64 + ((ks * 4 + g) ^ (rb & 7)) * 8);
      }
      #pragma unroll
      for (int mf = 0; mf < 4; ++mf)
        #pragma unroll
        for (int nf = 0; nf < 4; ++nf)
          acc[mf][nf] = mfma16(af[mf], bfr[nf], acc[mf][nf]);
    }
  }

  #pragma unroll
  for (int nf = 0; nf < 4; ++nf) {
    const int n = n0 + wn * 64 + nf * 16 + c;
    const float bv = bias[n];
    #pragma unroll
    for (int mf = 0; mf < 4; ++mf)
      #pragma unroll
      for (int r = 0; r < 4; ++r) {
        const int m = m0 + wm * 64 + mf * 16 + g * 4 + r;
        const float v = (acc[mf][nf][r] + bv) * qs;
        if (MODE == 0) {
          oF[(size_t)m * 512 + n] = v;
        } else {
          const int bb = m >> 12, s = m & 4095, h = n >> 6, hd = n & 63;
          if (z == 2)
            outb[(((size_t)(bb * 8 + h)) * 64 + hd) * 4096 + s] = f2bf(v);
          else
            outb[(((size_t)(bb * 8 + h)) * 4096 + s) * 64 + hd] = f2bf(v);
        }
      }
  }
}

// ---------------- flash attention v14 FINAL (proven 97.4-99.4us) ----------------
// Session ledger: 12 rounds, one real attn win (KVBLK=64->128, -4%). Null or
// regressive: XCD L3->L2 (null on time, -82% HBM fetch -- kept, harmless),
// LDS traffic -36%, occupancy halving, SW-pipelining, counted vmcnt,
// 32x32 in-register-P port (-9%: structure-specific ds_read conflicts),
// permlane swap (conflict-neutral), setprio (null x2 -- stripped here).
// Structural constraint at this floor: ~705 TF effective, bound by the
// interaction of MFMA (~2800 cyc/iter/SIMD), LDS pipe (~3300 cyc/iter/CU),
// and the serial QK->exp->pack->PV chain under the 2-phase barrier. The
// path past is the fully co-designed 4-cluster pipeline (T16-class);
// its first-order port measurably regressed. Non-attn (~103us) is
// harness-floor: invariant to GEMM rewrite, staging path, pass deletion.
// Structure: 512 thr / 8 waves x 32 q-rows; grid (16 qt, 16 bh) = 256
// blocks = 1/CU; KVBLK=128 dbuf; LDS 135 KB; XOR-swizzled K/V; Ps wave-
// local; l = P.1 on MFMA pipe; Q pre-scaled by sc*log2e; one
// __syncthreads/iter (deterministic by construction).
__global__ __launch_bounds__(512, 2) void attn(const USH* __restrict__ Qbuf,
                                               const USH* __restrict__ kv,
                                               USH* __restrict__ att) {
  __shared__ __align__(16) USH Ks[2 * 8192];    // [buf][half][key 0..127][32 USH]
  __shared__ __align__(16) USH Vt[2 * 8192];    // [buf][64 hd][128 USH]
  __shared__ __align__(16) USH Ps[8][32 * 140]; // per-wave [32 qrow][140 key-pad]
  __shared__ float lbuf[8][32];

  const int t = threadIdx.x;
  const int w = t >> 6, lane = t & 63;
  const int c = lane & 15, g = lane >> 4;
  // XCD-aware remap, bijective on [0,256): each XCD owns bh {xcd, xcd+8}
  // -> KV working set 2 MB <= per-XCD L2.
  const int linear = blockIdx.x + (blockIdx.y << 4);
  const int xcd = linear & 7, idx = linear >> 3;   // idx in [0,32)
  const int bh = xcd + ((idx >> 4) << 3);
  const int bb = bh >> 3, hh = bh & 7;
  const size_t base = (size_t)bh * 262144;  // 4096*64
  const USH* Q = Qbuf + base;
  const USH* K = kv + base;                 // [S,Hd]
  const USH* V = kv + 4194304 + base;       // [Hd,S] (pre-transposed)
  const int q0 = (idx & 15) * 256 + w * 32;

  // Q fragments (B-operand of S^T): registers for the whole K loop
  s16x8 qf[2][2];  // [qi][kh]
  #pragma unroll
  for (int qi = 0; qi < 2; ++qi)
    #pragma unroll
    for (int kh = 0; kh < 2; ++kh)
      qf[qi][kh] = *(const s16x8_a*)(Q + (size_t)(q0 + qi * 16 + c) * 64 + kh * 32 + g * 8);

  // constant ones-column B-fragment: l = P . 1 on the MFMA pipe
  s16x8 onesf;
  {
    const short one = (short)0x3F80, val = (c == 0) ? one : (short)0;
    #pragma unroll
    for (int j = 0; j < 8; ++j) onesf[j] = val;
  }

  f32x4 o[2][4] = {};
  f32x4 o_l[2] = {};

  // --- DMA lane mappings (8 waves, 2 calls each per K and V per tile) ---
  const int keyK = w * 16 + (lane >> 2);               // 0..127
  const int ccK = (lane & 3) ^ ((keyK >> 1) & 3);
  const USH* gK0 = K + (size_t)keyK * 64 + ccK * 8;    // +kt*8192 +j*32
  const int hdV = w * 4 + (lane >> 4);                 // 0..31, +j*32
  const int ccV = (lane & 15) ^ (hdV & 7);
  const USH* gV0 = V + (size_t)hdV * 4096 + ccV * 8;   // +kt*128 +j*131072
  USH* lK = Ks + w * 512 + lane * 8;   // +buf*8192 +j*4096
  USH* lV = Vt + w * 512 + lane * 8;   // +buf*8192 +j*4096

  // issue tile 0 -> buf 0
  #pragma unroll
  for (int j = 0; j < 2; ++j) {
    gld_lds16(gK0 + j * 32, lK + j * 4096);
    gld_lds16(gV0 + (size_t)j * 131072, lV + j * 4096);
  }

  for (int kt = 0; kt < 32; ++kt) {
    const int buf = kt & 1;
    __syncthreads();  // implicit vmcnt(0): tile kt resident; buf^1 free
    if (kt < 31) {    // issue tile kt+1 -> buf^1; flies across this iteration
      const int nb = (buf ^ 1) * 8192;
      #pragma unroll
      for (int j = 0; j < 2; ++j) {
        gld_lds16(gK0 + (size_t)(kt + 1) * 8192 + j * 32, lK + nb + j * 4096);
        gld_lds16(gV0 + (size_t)(kt + 1) * 128 + (size_t)j * 131072, lV + nb + j * 4096);
      }
    }

    // S^T[key][qrow] = K * Q^T  (Q pre-scaled; st IS the exp2 argument)
    f32x4 st[2][8] = {};
    #pragma unroll
    for (int kh = 0; kh < 2; ++kh) {
      s16x8 ak[8];
      #pragma unroll
      for (int kff = 0; kff < 8; ++kff) {
        const int row = kff * 16 + c;
        const int qsw = (g ^ ((c >> 1) & 3)) * 8;
        ak[kff] = *(const s16x8_a*)(Ks + buf * 8192 + kh * 4096 + row * 32 + qsw);
      }
      #pragma unroll
      for (int qi = 0; qi < 2; ++qi)
        #pragma unroll
        for (int kff = 0; kff < 8; ++kff)
          st[qi][kff] = mfma16(ak[kff], qf[qi][kh], st[qi][kff]);
    }

    // p = exp2(s); pack; write P to Ps[w] (wave-local; in-order DS)
    #pragma unroll
    for (int qi = 0; qi < 2; ++qi)
      #pragma unroll
      for (int kff = 0; kff < 8; ++kff) {
        #pragma unroll
        for (int r = 0; r < 4; ++r) st[qi][kff][r] = EXP2F(st[qi][kff][r]);
        const unsigned int lo = pk_bf16(st[qi][kff][0], st[qi][kff][1]);
        const unsigned int hi = pk_bf16(st[qi][kff][2], st[qi][kff][3]);
        *(u64_a*)(&Ps[w][(qi * 16 + c) * 140 + kff * 16 + g * 4]) =
            (unsigned long long)lo | ((unsigned long long)hi << 32);
      }

    // O[qrow][hd] += P * V ; l[qrow] += P . 1
    #pragma unroll
    for (int kf = 0; kf < 4; ++kf) {
      s16x8 ap[2];
      #pragma unroll
      for (int qi = 0; qi < 2; ++qi)
        ap[qi] = *(const s16x8_a*)(&Ps[w][(qi * 16 + c) * 140 + kf * 32 + g * 8]);
      s16x8 bv[4];
      #pragma unroll
      for (int hf = 0; hf < 4; ++hf) {
        const int qv = (((kf * 4 + g) ^ (c & 7))) * 8;
        bv[hf] = *(const s16x8_a*)(Vt + buf * 8192 + (c + 16 * hf) * 128 + qv);
      }
      #pragma unroll
      for (int qi = 0; qi < 2; ++qi) {
        #pragma unroll
        for (int hf = 0; hf < 4; ++hf)
          o[qi][hf] = mfma16(ap[qi], bv[hf], o[qi][hf]);
        o_l[qi] = mfma16(ap[qi], onesf, o_l[qi]);
      }
    }
  }

  // l lives in lanes c==0 (D[m][0]); broadcast within the wave via LDS
  if (c == 0) {
    #pragma unroll
    for (int qi = 0; qi < 2; ++qi)
      #pragma unroll
      for (int r = 0; r < 4; ++r) lbuf[w][qi * 16 + g * 4 + r] = o_l[qi][r];
  }
  __syncthreads();

  #pragma unroll
  for (int qi = 0; qi < 2; ++qi)
    #pragma unroll
    for (int r = 0; r < 4; ++r) {
      const int ml = qi * 16 + g * 4 + r;
      const float linv = 1.0f / lbuf[w][ml];
      const int qrow = q0 + ml;
      #pragma unroll
      for (int hf = 0; hf < 4; ++hf) {
        const int hd = c + 16 * hf;
        att[((size_t)(bb * 4096 + qrow)) * 512 + hh * 64 + hd] =
            f2bf(o[qi][hf][r] * linv);
      }
    }
}

extern "C" void kernel_launch(void* const* d_in, const int* in_sizes, int n_in,
                              void* d_out, int out_size, void* d_ws, size_t ws_size,
                              hipStream_t stream) {
  (void)in_sizes; (void)n_in; (void)out_size; (void)ws_size;
  const float* x  = (const float*)d_in[0];
  const float* Wq = (const float*)d_in[1];
  const float* bq = (const float*)d_in[2];
  const float* Wk = (const float*)d_in[3];
  const float* bk = (const float*)d_in[4];
  const float* Wv = (const float*)d_in[5];
  const float* bv = (const float*)d_in[6];
  const float* Wo = (const float*)d_in[7];
  const float* bo = (const float*)d_in[8];
  USH* ws  = (USH*)d_ws;
  USH* wT  = ws;                       // 4 * 262144 bf16 transposed weights (2 MB)
  USH* kv  = ws + 1048576;             // K [B,H,S,Hd] + V [B,H,Hd,S] bf16 (16 MB)
  USH* att = ws + 1048576 + 8388608;   // 4194304 : attn out [B,S,D] bf16 (8 MB)
  float* outF = (float*)d_out;         // fp32 output (16 MB)
  USH* qscratch = (USH*)d_out;         // Q bf16 (8 MB), dead before final GEMM

  prep<<<dim3(16, 16, 4), 256, 0, stream>>>(Wq, Wk, Wv, Wo, wT);
  gemm_bias<1><<<dim3(64, 4, 3), 256, 0, stream>>>(nullptr, x, wT, bq, bk, bv,
                                                   qscratch, kv, nullptr);
  attn<<<dim3(16, 16), 512, 0, stream>>>(qscratch, kv, att);
  gemm_bias<0><<<dim3(64, 4, 1), 256, 0, stream>>>(att, nullptr, wT + 3 * 262144,
                                                   bo, bo, bo,
                                                   nullptr, nullptr, outF);
}